// Round 5
// baseline (276.588 us; speedup 1.0000x reference)
//
#include <hip/hip_runtime.h>

// ---------------------------------------------------------------------------
// RelGraphConv x3 + action mask, MI355X (gfx950) — round 13
// R12 post-mortem: gather is at the per-CU MSHR/concurrency ceiling at
// L3-class latency (~50 lines in flight/CU at ~700ns); more per-wave MLP
// regressed. Lever = LATENCY: make gathers hit per-XCD L2.
//   * messages stored channel-SLICED: msgS[slice=ch>>3][rel*N+src][8ch],
//     8 slices x 1.6 MB; agg blocks pinned slice = blockIdx & 7 (round-robin
//     blockIdx->XCD heuristic) -> each XCD gathers within a resident 1.6 MB.
//   * agg_slice kernel: lane=(group g, ch8); per edge: coalesced id load +
//     16B row load (64 random lines in flight per instruction); per node a
//     7-shfl butterfly reduce-scatter delivers channel ch8 to lane ch8.
//   * ag2 unfused (phaseB + agg + gemm2); k3's gather -> 2nd agg pass;
//     k3 becomes transform-only. Dispatch boundaries are cheap (~0.7us).
// 8 dispatches: pack_init -> k1(bin||gemm1) -> phaseB -> agg1 -> gemm2 ->
//               agg2 -> k3' -> a3m_mask.
// ---------------------------------------------------------------------------

#define STRIDE 64    // bucket capacity; P(deg>=64) astronomically small
#define BINCAP 2560  // records per bin; mean 2048, sigma~45 -> 11 sigma margin

typedef unsigned short ushortT;
typedef __attribute__((ext_vector_type(8))) short short8;   // 8 bf16 (4 VGPRs)
typedef __attribute__((ext_vector_type(4))) float f32x4;    // MFMA C/D

__device__ inline ushortT f2bf(float f) {
    union { float f; unsigned u; } v; v.f = f;
    unsigned r = v.u + 0x7FFFu + ((v.u >> 16) & 1u);   // RNE
    return (ushortT)(r >> 16);
}
__device__ inline float bf2f(ushortT h) {
    union { unsigned u; float f; } v; v.u = ((unsigned)h) << 16;
    return v.f;
}

__device__ inline void atomicMinF(float* addr, float v) {
    if (v >= 0.f) atomicMin((int*)addr, __float_as_int(v));
    else          atomicMax((unsigned int*)addr, __float_as_uint(v));
}

// ---- K0: weight pack + bincnt/minval/done init -----------------------------
__global__ __launch_bounds__(256) void pack_init_kernel(
    const float* __restrict__ W1, const float* __restrict__ loop1,
    const float* __restrict__ W2, const float* __restrict__ loop2,
    ushortT* __restrict__ BP1, ushortT* __restrict__ BP2,
    int* __restrict__ bincnt, float* __restrict__ minval,
    int* __restrict__ done, int NBINS) {
    int g = (int)blockIdx.x * 256 + (int)threadIdx.x;  // 0..4607
    if (g < NBINS) bincnt[g] = 0;
    if (g == 0) { *(int*)minval = 0x7f7f7f7f; *done = 0; }
    if (g < 3072) {
        // layer 1: 12 ct x 4 ks x 64 lanes
        int l = g & 63, ks = (g >> 6) & 3, ct = g >> 8;
        int c = ct * 16 + (l & 15);
        int mat = c >> 6, cc = c & 63;
        int kbase = ks * 32 + (l >> 4) * 8;
        ushortT* dstp = BP1 + (size_t)g * 8;
#pragma unroll
        for (int j = 0; j < 8; ++j) {
            int k = kbase + j;
            float v = (mat < 2) ? W1[((size_t)mat * 128 + k) * 64 + cc]
                                : loop1[(size_t)k * 64 + cc];
            dstp[j] = f2bf(v);
        }
    } else {
        // layer 2: 12 ct x 2 ks x 64 lanes
        int s = g - 3072;
        int l = s & 63, ks = (s >> 6) & 1, ct = s >> 7;
        int c = ct * 16 + (l & 15);
        int mat = c >> 6, cc = c & 63;
        int kbase = ks * 32 + (l >> 4) * 8;
        ushortT* dstp = BP2 + (size_t)s * 8;
#pragma unroll
        for (int j = 0; j < 8; ++j) {
            int k = kbase + j;
            float v = (mat < 2) ? W2[((size_t)mat * 64 + k) * 64 + cc]
                                : loop2[(size_t)k * 64 + cc];
            dstp[j] = f2bf(v);
        }
    }
}

// ---- K1: phaseA-binning [0,NBA) | gemm1 [NBA, NBA+NTILES) ------------------
// gemm1 C-write: relation outputs go to SLICED layout hrelbS.
__global__ __launch_bounds__(256) void k1_kernel(
    const float* __restrict__ x, const ushortT* __restrict__ BP1,
    const float* __restrict__ b1,
    ushortT* __restrict__ hrelbS, ushortT* __restrict__ H1b,
    const int* __restrict__ src, const int* __restrict__ dst,
    const int* __restrict__ et, int* __restrict__ bincnt, int2* __restrict__ binbuf,
    int N, int E, int NBINS, int NBA) {
    __shared__ int hist[512];
    __shared__ int gbase[512];
    __shared__ ushortT rnk[4096];

    const int t = (int)threadIdx.x;
    const size_t N2 = (size_t)2 * N;

    if ((int)blockIdx.x < NBA) {
        // ---- phase A: bin 4096 edges ---------------------------------------
        for (int i = t; i < NBINS; i += 256) hist[i] = 0;
        __syncthreads();
        const int base = (int)blockIdx.x * 4096;
#pragma unroll
        for (int i = 0; i < 16; ++i) {
            int e = base + t + i * 256;
            if (e < E) {
                int bb = dst[e] >> 7;
                rnk[t + i * 256] = (ushortT)atomicAdd(&hist[bb], 1);
            }
        }
        __syncthreads();
        for (int i = t; i < NBINS; i += 256) {
            int h = hist[i];
            gbase[i] = h ? atomicAdd(&bincnt[i], h) : 0;
        }
        __syncthreads();
#pragma unroll
        for (int i = 0; i < 16; ++i) {
            int e = base + t + i * 256;
            if (e < E) {
                int dd = dst[e];
                int bb = dd >> 7;
                int v = et[e] * N + src[e];
                int pos = gbase[bb] + (int)rnk[t + i * 256];
                if (pos < BINCAP)
                    binbuf[(size_t)bb * BINCAP + pos] = make_int2(dd, v);
            }
        }
        return;
    }
    // ---- gemm1 (MFMA): wave = 16 nodes x 192 cols, K=128, no LDS use -------
    const int w = t >> 6, lane = t & 63;
    const int rowbase = (((int)blockIdx.x - NBA) * 4 + w) * 16;
    const int m = lane & 15, quad = lane >> 4;
    const int nclamp = min(rowbase + m, N - 1);

    short8 a[4];
    const float* xp = x + (size_t)nclamp * 128 + quad * 8;
#pragma unroll
    for (int ks = 0; ks < 4; ++ks) {
        float4 g0 = *(const float4*)(xp + ks * 32);
        float4 g1 = *(const float4*)(xp + ks * 32 + 4);
        a[ks][0] = (short)f2bf(g0.x); a[ks][1] = (short)f2bf(g0.y);
        a[ks][2] = (short)f2bf(g0.z); a[ks][3] = (short)f2bf(g0.w);
        a[ks][4] = (short)f2bf(g1.x); a[ks][5] = (short)f2bf(g1.y);
        a[ks][6] = (short)f2bf(g1.z); a[ks][7] = (short)f2bf(g1.w);
    }

    f32x4 acc[12];
#pragma unroll
    for (int ct = 0; ct < 12; ++ct) acc[ct] = (f32x4){0.f, 0.f, 0.f, 0.f};

#pragma unroll
    for (int ks = 0; ks < 4; ++ks) {
#pragma unroll
        for (int ct = 0; ct < 12; ++ct) {
            short8 b = *(const short8*)&BP1[((size_t)(ct * 4 + ks) * 64 + lane) * 8];
            acc[ct] = __builtin_amdgcn_mfma_f32_16x16x32_bf16(a[ks], b, acc[ct], 0, 0, 0);
        }
    }

    const int node0 = rowbase + quad * 4;
#pragma unroll
    for (int ct = 0; ct < 12; ++ct) {
        int c = ct * 16 + m;
        int mat = c >> 6, cc = c & 63;
        float bias = (mat == 2) ? b1[cc] : 0.f;
#pragma unroll
        for (int j = 0; j < 4; ++j) {
            int n = node0 + j;
            if (n < N) {
                float v = acc[ct][j] + bias;
                if (mat < 2)
                    hrelbS[((size_t)(cc >> 3) * N2 + (size_t)mat * N + n) * 8 + (cc & 7)] = f2bf(v);
                else
                    H1b[(size_t)n * 64 + cc] = f2bf(v);
            }
        }
    }
}

// ---- K2: phase B — block per bin, LDS counting, local eidx writes ----------
__global__ __launch_bounds__(256) void phaseB_kernel(
    const int* __restrict__ bincnt, const int2* __restrict__ binbuf,
    int* __restrict__ cnt, int* __restrict__ eidx, int N) {
    __shared__ int lcnt[128];
    const int b = (int)blockIdx.x;
    const int t = (int)threadIdx.x;
    if (t < 128) lcnt[t] = 0;
    __syncthreads();
    const int cb = min(bincnt[b], BINCAP);
    const int2* buf = binbuf + (size_t)b * BINCAP;
    for (int i = t; i < cb; i += 256) {
        int2 rec = buf[i];
        int r = atomicAdd(&lcnt[rec.x & 127], 1);
        if (r < STRIDE) eidx[(size_t)rec.x * STRIDE + r] = rec.y;
    }
    __syncthreads();
    int node = b * 128 + t;
    if (t < 128 && node < N) cnt[node] = min(lcnt[t], STRIDE);
}

// ---- AGG: channel-sliced XCD-pinned gather-aggregate + relu ----------------
// slice = blockIdx & 7 (round-robin blockIdx->XCD). Lane = (group g, ch8);
// per edge e (= ch8 + 8k): id load + 16B row load; butterfly reduce-scatter
// (verified: lane ch8 ends with channel ch8's total). In-place on H:
// reads self H[node*64 + s*8+ch8], writes relu(self+agg) to same address.
__global__ __launch_bounds__(256) void agg_slice_kernel(
    const ushortT* __restrict__ msgS, const int* __restrict__ eidx,
    const int* __restrict__ cnt, ushortT* __restrict__ H, int N) {
    const int b = (int)blockIdx.x;
    const int s = b & 7;
    const int t = (int)threadIdx.x;
    const int w = t >> 6, lane = t & 63;
    const int g = lane >> 3, ch8 = lane & 7;
    const int node = (b >> 3) * 32 + w * 8 + g;
    if (node >= N) return;

    const int deg = cnt[node];
    const ushortT* base = msgS + (size_t)s * 2 * N * 8;
    const int* row = eidx + (size_t)node * STRIDE;

    float acc[8] = {0.f, 0.f, 0.f, 0.f, 0.f, 0.f, 0.f, 0.f};
    for (int e = ch8; e < deg; e += 8) {
        int id = row[e];                                   // coalesced 4B
        uint4 rv = *(const uint4*)(base + (size_t)id * 8); // 16B slice row
        acc[0] += bf2f((ushortT)(rv.x & 0xffff));
        acc[1] += bf2f((ushortT)(rv.x >> 16));
        acc[2] += bf2f((ushortT)(rv.y & 0xffff));
        acc[3] += bf2f((ushortT)(rv.y >> 16));
        acc[4] += bf2f((ushortT)(rv.z & 0xffff));
        acc[5] += bf2f((ushortT)(rv.z >> 16));
        acc[6] += bf2f((ushortT)(rv.w & 0xffff));
        acc[7] += bf2f((ushortT)(rv.w >> 16));
    }
    // butterfly reduce-scatter across the 8-lane group:
    // after r1: a4[q] = ch (2q + (ch8&1)) over lane-pair
    // after r2: a2[q] = ch (4q + (ch8&3)) over quad
    // after r3: tot   = ch ch8 over all 8 lanes
    float a4[4];
#pragma unroll
    for (int q = 0; q < 4; ++q) {
        float sendv = (ch8 & 1) ? acc[2 * q] : acc[2 * q + 1];
        float keepv = (ch8 & 1) ? acc[2 * q + 1] : acc[2 * q];
        a4[q] = keepv + __shfl_xor(sendv, 1, 64);
    }
    float a2[2];
#pragma unroll
    for (int q = 0; q < 2; ++q) {
        float sendv = (ch8 & 2) ? a4[2 * q] : a4[2 * q + 1];
        float keepv = (ch8 & 2) ? a4[2 * q + 1] : a4[2 * q];
        a2[q] = keepv + __shfl_xor(sendv, 2, 64);
    }
    float sendv = (ch8 & 4) ? a2[0] : a2[1];
    float keepv = (ch8 & 4) ? a2[1] : a2[0];
    float tot = keepv + __shfl_xor(sendv, 4, 64);

    size_t hoff = (size_t)node * 64 + s * 8 + ch8;
    float r = fmaxf(bf2f(H[hoff]) + tot, 0.f);             // self + agg, relu
    H[hoff] = f2bf(r);
}

// ---- gemm2 (MFMA): wave = 16 nodes x 192 cols, K=64; sliced rel C-write ----
__global__ __launch_bounds__(256) void gemm2_mfma(
    const ushortT* __restrict__ H1b, const ushortT* __restrict__ BP2,
    const float* __restrict__ b2,
    ushortT* __restrict__ hrel2bS, ushortT* __restrict__ H2b, int N) {
    const int w = (int)threadIdx.x >> 6, lane = (int)threadIdx.x & 63;
    const int rowbase = ((int)blockIdx.x * 4 + w) * 16;
    const int m = lane & 15, quad = lane >> 4;
    const int nclamp = min(rowbase + m, N - 1);
    const size_t N2 = (size_t)2 * N;

    short8 a[2];
    const ushortT* hp = H1b + (size_t)nclamp * 64 + quad * 8;
    a[0] = *(const short8*)(hp);
    a[1] = *(const short8*)(hp + 32);

    f32x4 acc[12];
#pragma unroll
    for (int ct = 0; ct < 12; ++ct) acc[ct] = (f32x4){0.f, 0.f, 0.f, 0.f};

#pragma unroll
    for (int ks = 0; ks < 2; ++ks) {
#pragma unroll
        for (int ct = 0; ct < 12; ++ct) {
            short8 b = *(const short8*)&BP2[((size_t)(ct * 2 + ks) * 64 + lane) * 8];
            acc[ct] = __builtin_amdgcn_mfma_f32_16x16x32_bf16(a[ks], b, acc[ct], 0, 0, 0);
        }
    }

    const int node0 = rowbase + quad * 4;
#pragma unroll
    for (int ct = 0; ct < 12; ++ct) {
        int c = ct * 16 + m;
        int mat = c >> 6, cc = c & 63;
        float bias = (mat == 2) ? b2[cc] : 0.f;
#pragma unroll
        for (int j = 0; j < 4; ++j) {
            int n = node0 + j;
            if (n < N) {
                float v = acc[ct][j] + bias;
                if (mat < 2)
                    hrel2bS[((size_t)(cc >> 3) * N2 + (size_t)mat * N + n) * 8 + (cc & 7)] = f2bf(v);
                else
                    H2b[(size_t)n * 64 + cc] = f2bf(v);
            }
        }
    }
}

// ---- K3': layer-3 transform only (agg done by agg_slice pass 2) ------------
__global__ void k3p_kernel(const ushortT* __restrict__ H2b,
                           const float* __restrict__ W3, const float* __restrict__ loop3,
                           const float* __restrict__ b3,
                           float* __restrict__ hrel3, float* __restrict__ H3, int N) {
    int node = (int)blockIdx.x * 4 + ((int)threadIdx.x >> 6);
    if (node >= N) return;
    int lane = (int)threadIdx.x & 63;
    float xk = bf2f(H2b[(size_t)node * 64 + lane]);  // final h2 (already relu)
    float p[6];
    p[0] = xk * W3[lane * 2 + 0];
    p[1] = xk * W3[lane * 2 + 1];
    p[2] = xk * W3[(64 + lane) * 2 + 0];
    p[3] = xk * W3[(64 + lane) * 2 + 1];
    p[4] = xk * loop3[lane * 2 + 0];
    p[5] = xk * loop3[lane * 2 + 1];
#pragma unroll
    for (int mm = 32; mm >= 1; mm >>= 1) {
#pragma unroll
        for (int q = 0; q < 6; ++q) p[q] += __shfl_xor(p[q], mm, 64);
    }
    if (lane == 0) {
        hrel3[(size_t)node * 2 + 0] = p[0];
        hrel3[(size_t)node * 2 + 1] = p[1];
        hrel3[((size_t)N + node) * 2 + 0] = p[2];
        hrel3[((size_t)N + node) * 2 + 1] = p[3];
        H3[(size_t)node * 2 + 0] = p[4] + b3[0];
        H3[(size_t)node * 2 + 1] = p[5] + b3[1];
    }
}

// ---- A3M+MASK: layer-3 agg + global min (196-block spin barrier) + mask ----
__global__ __launch_bounds__(256) void a3m_mask_kernel(
    const float* __restrict__ hrel3, const int* __restrict__ eidx,
    const int* __restrict__ cnt, const float* __restrict__ H3,
    const int* __restrict__ cs, const int* __restrict__ ms,
    float* __restrict__ minval, int* __restrict__ done,
    float* __restrict__ out, int N) {
    const int t = (int)threadIdx.x;
    const int n = (int)blockIdx.x * 256 + t;
    float a0 = 0.f, a1 = 0.f;
    float v = 3.4e38f;
    if (n < N) {
        a0 = H3[n * 2 + 0]; a1 = H3[n * 2 + 1];
        int deg = cnt[n];
        const int* row = &eidx[(size_t)n * STRIDE];
        int j = 0;
        for (; j + 3 < deg; j += 4) {
            int i0 = row[j], i1 = row[j + 1], i2 = row[j + 2], i3 = row[j + 3];
            float2 q0 = *(const float2*)&hrel3[(size_t)i0 * 2];
            float2 q1 = *(const float2*)&hrel3[(size_t)i1 * 2];
            float2 q2 = *(const float2*)&hrel3[(size_t)i2 * 2];
            float2 q3 = *(const float2*)&hrel3[(size_t)i3 * 2];
            a0 += (q0.x + q1.x) + (q2.x + q3.x);
            a1 += (q0.y + q1.y) + (q2.y + q3.y);
        }
        for (; j < deg; ++j) {
            float2 q = *(const float2*)&hrel3[(size_t)row[j] * 2];
            a0 += q.x; a1 += q.y;
        }
        v = fminf(a0, a1);       // h.min() over FINAL h, before masking
    }
#pragma unroll
    for (int mm = 32; mm >= 1; mm >>= 1) v = fminf(v, __shfl_xor(v, mm, 64));
    __shared__ float s[4];
    __shared__ float gm;
    if ((t & 63) == 0) s[t >> 6] = v;
    __syncthreads();
    if (t == 0) {
        atomicMinF(minval, fminf(fminf(s[0], s[1]), fminf(s[2], s[3])));
        __threadfence();                        // order minval before done
        atomicAdd(done, 1);
        while (atomicAdd(done, 0) < (int)gridDim.x)  // 196 pollers: proven OK
            __builtin_amdgcn_s_sleep(2);
        gm = atomicAdd(minval, 0.0f);           // atomic read of final min
    }
    __syncthreads();
    if (n < N) {
        float mn = gm - 1.0f;
        bool up = cs[n] >= ms[n] - 1;
        bool lo = cs[n] == 0;
        out[n * 2 + 0] = up ? mn : a0;
        out[n * 2 + 1] = lo ? mn : a1;
    }
}

// ---------------------------------------------------------------------------
extern "C" void kernel_launch(void* const* d_in, const int* in_sizes, int n_in,
                              void* d_out, int out_size, void* d_ws, size_t ws_size,
                              hipStream_t stream) {
    const float* x     = (const float*)d_in[0];
    const int* src     = (const int*)d_in[1];
    const int* dst     = (const int*)d_in[2];
    const int* etypes  = (const int*)d_in[3];
    const int* cellsz  = (const int*)d_in[4];
    const int* maxsz   = (const int*)d_in[5];
    const float* W1    = (const float*)d_in[6];
    const float* loop1 = (const float*)d_in[7];
    const float* b1    = (const float*)d_in[8];
    const float* W2    = (const float*)d_in[9];
    const float* loop2 = (const float*)d_in[10];
    const float* b2    = (const float*)d_in[11];
    const float* W3    = (const float*)d_in[12];
    const float* loop3 = (const float*)d_in[13];
    const float* b3    = (const float*)d_in[14];
    float* out = (float*)d_out;

    const int N = in_sizes[0] / 128;  // 50000
    const int E = in_sizes[1];        // 800000

    char* p = (char*)d_ws;
    auto alloc = [&](size_t bytes) -> void* {
        void* r = (void*)p;
        p += ((bytes + 255) / 256) * 256;
        return r;
    };
    ushortT* hrelbS  = (ushortT*)alloc((size_t)2 * N * 64 * 2);  // 12.8 MB sliced
    ushortT* H1b     = (ushortT*)alloc((size_t)N * 64 * 2);      //  6.4 MB bf16
    ushortT* hrel2bS = (ushortT*)alloc((size_t)2 * N * 64 * 2);  // 12.8 MB sliced
    ushortT* H2b     = (ushortT*)alloc((size_t)N * 64 * 2);      //  6.4 MB bf16
    float* hrel3     = (float*)alloc((size_t)2 * N * 2 * 4);
    float* H3        = (float*)alloc((size_t)N * 2 * 4);
    int* cnt         = (int*)alloc((size_t)N * 4);
    int* eidx        = (int*)alloc((size_t)N * STRIDE * 4);      // 12.8 MB
    ushortT* BP1     = (ushortT*)alloc((size_t)3072 * 8 * 2);    // 48 KB frag-packed
    ushortT* BP2     = (ushortT*)alloc((size_t)1536 * 8 * 2);    // 24 KB
    float* minval    = (float*)alloc(4);
    int* done        = (int*)alloc(4);                           // own 256B chunk

    const int NBINS = (N + 127) >> 7;                           // 391
    int* bincnt     = (int*)alloc((size_t)NBINS * 4);
    int2* binbuf    = (int2*)alloc((size_t)NBINS * BINCAP * 8); // 8.0 MB
    (void)ws_size; (void)n_in; (void)out_size;

    const int NB_N   = (N + 255) / 256;      // 196
    const int NTILES = (N + 63) / 64;        // 782
    const int NB_W   = (N + 3) / 4;          // 12500
    const int NBA    = (E + 4095) / 4096;    // 196 phase-A blocks
    const int NB_AGG = ((N + 31) / 32) * 8;  // 12504 (slice = blockIdx & 7)

    // K0: weight pack + bincnt/minval/done init
    pack_init_kernel<<<18, 256, 0, stream>>>(
        W1, loop1, W2, loop2, BP1, BP2, bincnt, minval, done, NBINS);

    // K1: phase-A binning || layer-1 MFMA GEMM (sliced rel writes)
    k1_kernel<<<NBA + NTILES, 256, 0, stream>>>(
        x, BP1, b1, hrelbS, H1b,
        src, dst, etypes, bincnt, binbuf, N, E, NBINS, NBA);

    // phase B: bin-local scatter into eidx buckets + cnt
    phaseB_kernel<<<NBINS, 256, 0, stream>>>(bincnt, binbuf, cnt, eidx, N);

    // layer-1 aggregation: channel-sliced, XCD-pinned
    agg_slice_kernel<<<NB_AGG, 256, 0, stream>>>(hrelbS, eidx, cnt, H1b, N);

    // layer-2 GEMM (MFMA), sliced rel writes
    gemm2_mfma<<<NTILES, 256, 0, stream>>>(H1b, BP2, b2, hrel2bS, H2b, N);

    // layer-2 aggregation: channel-sliced, XCD-pinned
    agg_slice_kernel<<<NB_AGG, 256, 0, stream>>>(hrel2bS, eidx, cnt, H2b, N);

    // layer-3 transform (agg for layer 3 happens in a3m)
    k3p_kernel<<<NB_W, 256, 0, stream>>>(H2b, W3, loop3, b3, hrel3, H3, N);

    // layer-3 aggregation + global min (spin barrier) + mask
    a3m_mask_kernel<<<NB_N, 256, 0, stream>>>(hrel3, eidx, cnt, H3,
                                              cellsz, maxsz, minval, done, out, N);
}

// Round 7
// 230.952 us; speedup vs baseline: 1.1976x; 1.1976x over previous
//
#include <hip/hip_runtime.h>

// ---------------------------------------------------------------------------
// RelGraphConv x3 + action mask, MI355X (gfx950) — round 14 (resubmit; R6's
// bench was an infra failure: "container failed twice", kernel never ran)
// R13 post-mortem: per-pass time invariant (~43-45us) across request size /
// MLP / occupancy / XCD-pinning; FETCH matches COMPULSORY traffic; eff HBM
// 1.3-1.6 TB/s. => gathers are bounded by compulsory workspace traffic at
// random-granule efficiency. Lever: eliminate bytes.
// This round: aggregate-then-transform on layer 2:
//   h2 = relu(W2_0@A0 + W2_1@A1 + loop2@h1 + b2),  A_r = sum_{j->i,r} h1[j]
// Gather reads h1 rows directly (same 1 req/edge, 6.4MB footprint);
// per-relation sums in registers; one K=192 MFMA per 64-node tile.
// hrel2b (25.6 MB/iter of HBM traffic) is ELIMINATED.
// 6 dispatches: K0 -> K1(bin||gemm1) -> AG1(phase0+agg1) -> AG2p(agg2+gemm2)
//               -> K3p(coalesced l3 transform) -> A3M(l3 agg+min+mask).
// ---------------------------------------------------------------------------

#define STRIDE 64    // bucket capacity; P(deg>=64) astronomically small
#define BINCAP 2560  // records per bin; mean 2048, sigma~45 -> 11 sigma margin

typedef unsigned short ushortT;
typedef __attribute__((ext_vector_type(8))) short short8;   // 8 bf16 (4 VGPRs)
typedef __attribute__((ext_vector_type(4))) float f32x4;    // MFMA C/D

__device__ inline ushortT f2bf(float f) {
    union { float f; unsigned u; } v; v.f = f;
    unsigned r = v.u + 0x7FFFu + ((v.u >> 16) & 1u);   // RNE
    return (ushortT)(r >> 16);
}
__device__ inline float bf2f(ushortT h) {
    union { unsigned u; float f; } v; v.u = ((unsigned)h) << 16;
    return v.f;
}

__device__ inline void atomicMinF(float* addr, float v) {
    if (v >= 0.f) atomicMin((int*)addr, __float_as_int(v));
    else          atomicMax((unsigned int*)addr, __float_as_uint(v));
}

// ---- K0: weight pack + bincnt/minval/done init -----------------------------
// BP1: gemm1 (out=192: W1_0|W1_1|loop1 stacked in ct, K=128)  [R9 layout]
// BP2p: AG2p (out=64, K=192: [W2_0;W2_1;loop2] stacked in K)  [new]
__global__ __launch_bounds__(256) void pack_init_kernel(
    const float* __restrict__ W1, const float* __restrict__ loop1,
    const float* __restrict__ W2, const float* __restrict__ loop2,
    ushortT* __restrict__ BP1, ushortT* __restrict__ BP2p,
    int* __restrict__ bincnt, float* __restrict__ minval,
    int* __restrict__ done, int NBINS) {
    int g = (int)blockIdx.x * 256 + (int)threadIdx.x;  // 0..4607
    if (g < NBINS) bincnt[g] = 0;
    if (g == 0) { *(int*)minval = 0x7f7f7f7f; *done = 0; }
    if (g < 3072) {
        // layer 1: 12 ct x 4 ks x 64 lanes (unchanged from R9)
        int l = g & 63, ks = (g >> 6) & 3, ct = g >> 8;
        int c = ct * 16 + (l & 15);
        int mat = c >> 6, cc = c & 63;
        int kbase = ks * 32 + (l >> 4) * 8;
        ushortT* dstp = BP1 + (size_t)g * 8;
#pragma unroll
        for (int j = 0; j < 8; ++j) {
            int k = kbase + j;
            float v = (mat < 2) ? W1[((size_t)mat * 128 + k) * 64 + cc]
                                : loop1[(size_t)k * 64 + cc];
            dstp[j] = f2bf(v);
        }
    } else {
        // layer 2 stacked-K: 4 ct x 6 ks x 64 lanes; s = ct*384 + ks*64 + l
        int s = g - 3072;
        int l = s & 63, ks = (s >> 6) % 6, ct = s / 384;
        int c = ct * 16 + (l & 15);                 // out col 0..63
        int kbase = ks * 32 + (l >> 4) * 8;         // K 0..191
        ushortT* dstp = BP2p + (size_t)s * 8;
#pragma unroll
        for (int j = 0; j < 8; ++j) {
            int k = kbase + j;
            // K-layout [A0|A1|h1self]: k<128 -> W2flat[k][c] ([2][64][64] flat
            // = [128][64]); k>=128 -> loop2[k-128][c]
            float v = (k < 128) ? W2[(size_t)k * 64 + c]
                                : loop2[(size_t)(k - 128) * 64 + c];
            dstp[j] = f2bf(v);
        }
    }
}

// ---- K1: phaseA-binning [0,NBA) | gemm1 [NBA, NBA+NTILES) ------------------
// (EXACT R9 copy — proven at 218.5us)
__global__ __launch_bounds__(256) void k1_kernel(
    const float* __restrict__ x, const ushortT* __restrict__ BP1,
    const float* __restrict__ b1,
    ushortT* __restrict__ hrelb, ushortT* __restrict__ H1b,
    const int* __restrict__ src, const int* __restrict__ dst,
    const int* __restrict__ et, int* __restrict__ bincnt, int2* __restrict__ binbuf,
    int N, int E, int NBINS, int NBA) {
    __shared__ int hist[512];
    __shared__ int gbase[512];
    __shared__ ushortT rnk[4096];

    const int t = (int)threadIdx.x;

    if ((int)blockIdx.x < NBA) {
        for (int i = t; i < NBINS; i += 256) hist[i] = 0;
        __syncthreads();
        const int base = (int)blockIdx.x * 4096;
#pragma unroll
        for (int i = 0; i < 16; ++i) {
            int e = base + t + i * 256;
            if (e < E) {
                int bb = dst[e] >> 7;
                rnk[t + i * 256] = (ushortT)atomicAdd(&hist[bb], 1);
            }
        }
        __syncthreads();
        for (int i = t; i < NBINS; i += 256) {
            int h = hist[i];
            gbase[i] = h ? atomicAdd(&bincnt[i], h) : 0;
        }
        __syncthreads();
#pragma unroll
        for (int i = 0; i < 16; ++i) {
            int e = base + t + i * 256;
            if (e < E) {
                int dd = dst[e];
                int bb = dd >> 7;
                int v = et[e] * N + src[e];
                int pos = gbase[bb] + (int)rnk[t + i * 256];
                if (pos < BINCAP)
                    binbuf[(size_t)bb * BINCAP + pos] = make_int2(dd, v);
            }
        }
        return;
    }
    const int w = t >> 6, lane = t & 63;
    const int rowbase = (((int)blockIdx.x - NBA) * 4 + w) * 16;
    const int m = lane & 15, quad = lane >> 4;
    const int nclamp = min(rowbase + m, N - 1);

    short8 a[4];
    const float* xp = x + (size_t)nclamp * 128 + quad * 8;
#pragma unroll
    for (int ks = 0; ks < 4; ++ks) {
        float4 g0 = *(const float4*)(xp + ks * 32);
        float4 g1 = *(const float4*)(xp + ks * 32 + 4);
        a[ks][0] = (short)f2bf(g0.x); a[ks][1] = (short)f2bf(g0.y);
        a[ks][2] = (short)f2bf(g0.z); a[ks][3] = (short)f2bf(g0.w);
        a[ks][4] = (short)f2bf(g1.x); a[ks][5] = (short)f2bf(g1.y);
        a[ks][6] = (short)f2bf(g1.z); a[ks][7] = (short)f2bf(g1.w);
    }

    f32x4 acc[12];
#pragma unroll
    for (int ct = 0; ct < 12; ++ct) acc[ct] = (f32x4){0.f, 0.f, 0.f, 0.f};

#pragma unroll
    for (int ks = 0; ks < 4; ++ks) {
#pragma unroll
        for (int ct = 0; ct < 12; ++ct) {
            short8 b = *(const short8*)&BP1[((size_t)(ct * 4 + ks) * 64 + lane) * 8];
            acc[ct] = __builtin_amdgcn_mfma_f32_16x16x32_bf16(a[ks], b, acc[ct], 0, 0, 0);
        }
    }

    const int node0 = rowbase + quad * 4;
#pragma unroll
    for (int ct = 0; ct < 12; ++ct) {
        int c = ct * 16 + m;
        int mat = c >> 6, cc = c & 63;
        float bias = (mat == 2) ? b1[cc] : 0.f;
#pragma unroll
        for (int j = 0; j < 4; ++j) {
            int n = node0 + j;
            if (n < N) {
                float v = acc[ct][j] + bias;
                if (mat < 2) hrelb[((size_t)mat * N + n) * 64 + cc] = f2bf(v);
                else         H1b[(size_t)n * 64 + cc] = f2bf(v);
            }
        }
    }
}

// ---- AG1: phase0 (half-bin scatter) + agg(layer1) -> h1 in-place -----------
// = R9 ag2 minus its gemm2 tail: writes relu(self+agg) straight to H1b.
__global__ __launch_bounds__(512, 4) void ag1_kernel(
    const ushortT* __restrict__ hrelb,
    const int* __restrict__ bincnt, const int2* __restrict__ binbuf,
    int* __restrict__ eidx, int* __restrict__ cnt,
    ushortT* __restrict__ H1b, int N) {
    __shared__ int lcnt[64];
    __shared__ int lidx[64][STRIDE];                       // 16 KB

    const int t = (int)threadIdx.x;
    const int B = (int)blockIdx.x;
    const int nodeBase = B * 64;
    const int bin = B >> 1;

    if (t < 64) lcnt[t] = 0;
    __syncthreads();

    const int cb = min(bincnt[bin], BINCAP);
    const int2* buf = binbuf + (size_t)bin * BINCAP;
    for (int i = t; i < cb; i += 512) {
        int2 rec = buf[i];
        int local = rec.x - nodeBase;
        if ((unsigned)local < 64u) {
            int r = atomicAdd(&lcnt[local], 1);
            if (r < STRIDE) {
                lidx[local][r] = rec.y;
                eidx[(size_t)rec.x * STRIDE + r] = rec.y;   // for AG2p/A3M
            }
        }
    }
    __syncthreads();
    if (t < 64) {
        int c = min(lcnt[t], STRIDE);
        lcnt[t] = c;
        int node = nodeBase + t;
        if (node < N) cnt[node] = c;
    }
    __syncthreads();

    const int w = t >> 6, lane = t & 63;
    for (int i = 0; i < 8; ++i) {
        int local = w * 8 + i;
        int node = nodeBase + local;
        if (node >= N) continue;
        int deg = lcnt[local];
        float acc = bf2f(H1b[(size_t)node * 64 + lane]);   // self-loop + bias
        int j = 0;
        for (; j + 7 < deg; j += 8) {
            float v[8];
#pragma unroll
            for (int q = 0; q < 8; ++q) {
                int id = lidx[local][j + q];               // LDS broadcast
                v[q] = bf2f(hrelb[(size_t)id * 64 + lane]);
            }
            acc += ((v[0] + v[1]) + (v[2] + v[3])) + ((v[4] + v[5]) + (v[6] + v[7]));
        }
        for (; j < deg; ++j)
            acc += bf2f(hrelb[(size_t)lidx[local][j] * 64 + lane]);
        H1b[(size_t)node * 64 + lane] = f2bf(fmaxf(acc, 0.f));  // h1, in place
    }
}

// ---- AG2p: agg(layer2 in h1-space) + K=192 MFMA -> h2 (no hrel2b!) ---------
// Per 64-node tile: 8 waves x 8 nodes gather h1 rows per edge, accumulate
// per-relation sums A0,A1 in fp32 regs (lane=channel), stage [A0|A1|h1self]
// bf16 in LDS, then one K=192 MFMA (out=64) -> relu -> H2b.
__global__ __launch_bounds__(512, 4) void ag2p_kernel(
    const ushortT* __restrict__ H1b, const ushortT* __restrict__ BP2p,
    const float* __restrict__ b2,
    const int* __restrict__ eidx, const int* __restrict__ cnt,
    ushortT* __restrict__ H2b, int N) {
    __shared__ __align__(16) ushortT As[64 * 200];         // 25.6 KB, pad 192->200

    const int t = (int)threadIdx.x;
    const int nodeBase = (int)blockIdx.x * 64;
    const int w = t >> 6, lane = t & 63;

    for (int i = 0; i < 8; ++i) {
        const int local = w * 8 + i;
        const int node = nodeBase + local;
        float a0 = 0.f, a1 = 0.f;
        ushortT selfb = 0;
        if (node < N) {
            const int deg = cnt[node];
            int my = eidx[(size_t)node * STRIDE + lane];
            selfb = H1b[(size_t)node * 64 + lane];
            int j = 0;
            for (; j + 7 < deg; j += 8) {
                int vv[8];
                float vl[8];
#pragma unroll
                for (int q = 0; q < 8; ++q) vv[q] = __shfl(my, j + q, 64);
#pragma unroll
                for (int q = 0; q < 8; ++q) {
                    int s = (vv[q] >= N) ? vv[q] - N : vv[q];
                    vl[q] = bf2f(H1b[(size_t)s * 64 + lane]);
                }
#pragma unroll
                for (int q = 0; q < 8; ++q) {
                    bool r = vv[q] >= N;
                    a0 += r ? 0.f : vl[q];
                    a1 += r ? vl[q] : 0.f;
                }
            }
            for (; j < deg; ++j) {
                int v = __shfl(my, j, 64);
                bool r = v >= N;
                float val = bf2f(H1b[(size_t)(r ? v - N : v) * 64 + lane]);
                a0 += r ? 0.f : val;
                a1 += r ? val : 0.f;
            }
        }
        As[local * 200 + lane]       = f2bf(a0);
        As[local * 200 + 64 + lane]  = f2bf(a1);
        As[local * 200 + 128 + lane] = selfb;              // h1 self, bit-exact
    }
    __syncthreads();

    // MFMA: 8 waves = 4 row-tiles x 2 col-halves; K=192 (6 ks), out=64.
    const int rt = w & 3, h = w >> 2;
    const int m = lane & 15, quad = lane >> 4;
    f32x4 acc2[2];
    acc2[0] = (f32x4){0.f, 0.f, 0.f, 0.f};
    acc2[1] = (f32x4){0.f, 0.f, 0.f, 0.f};
#pragma unroll
    for (int ks = 0; ks < 6; ++ks) {
        short8 a = *(const short8*)&As[(rt * 16 + m) * 200 + quad * 8 + ks * 32];
#pragma unroll
        for (int c2 = 0; c2 < 2; ++c2) {
            int ct = h * 2 + c2;
            short8 b = *(const short8*)&BP2p[((size_t)(ct * 6 + ks) * 64 + lane) * 8];
            acc2[c2] = __builtin_amdgcn_mfma_f32_16x16x32_bf16(a, b, acc2[c2], 0, 0, 0);
        }
    }
    const int node0 = nodeBase + rt * 16 + quad * 4;
#pragma unroll
    for (int c2 = 0; c2 < 2; ++c2) {
        int c = (h * 2 + c2) * 16 + m;
        float bias = b2[c];
#pragma unroll
        for (int j = 0; j < 4; ++j) {
            int n = node0 + j;
            if (n < N)
                H2b[(size_t)n * 64 + c] = f2bf(fmaxf(acc2[c2][j] + bias, 0.f));
        }
    }
}

// ---- K3p: layer-3 transform only (coalesced; h2 already relu'd) ------------
__global__ void k3p_kernel(const ushortT* __restrict__ H2b,
                           const float* __restrict__ W3, const float* __restrict__ loop3,
                           const float* __restrict__ b3,
                           float* __restrict__ hrel3, float* __restrict__ H3, int N) {
    int node = (int)blockIdx.x * 4 + ((int)threadIdx.x >> 6);
    if (node >= N) return;
    int lane = (int)threadIdx.x & 63;
    float xk = bf2f(H2b[(size_t)node * 64 + lane]);
    float p[6];
    p[0] = xk * W3[lane * 2 + 0];
    p[1] = xk * W3[lane * 2 + 1];
    p[2] = xk * W3[(64 + lane) * 2 + 0];
    p[3] = xk * W3[(64 + lane) * 2 + 1];
    p[4] = xk * loop3[lane * 2 + 0];
    p[5] = xk * loop3[lane * 2 + 1];
#pragma unroll
    for (int mm = 32; mm >= 1; mm >>= 1) {
#pragma unroll
        for (int q = 0; q < 6; ++q) p[q] += __shfl_xor(p[q], mm, 64);
    }
    if (lane == 0) {
        hrel3[(size_t)node * 2 + 0] = p[0];
        hrel3[(size_t)node * 2 + 1] = p[1];
        hrel3[((size_t)N + node) * 2 + 0] = p[2];
        hrel3[((size_t)N + node) * 2 + 1] = p[3];
        H3[(size_t)node * 2 + 0] = p[4] + b3[0];
        H3[(size_t)node * 2 + 1] = p[5] + b3[1];
    }
}

// ---- A3M+MASK: layer-3 agg + global min (196-block spin barrier) + mask ----
__global__ __launch_bounds__(256) void a3m_mask_kernel(
    const float* __restrict__ hrel3, const int* __restrict__ eidx,
    const int* __restrict__ cnt, const float* __restrict__ H3,
    const int* __restrict__ cs, const int* __restrict__ ms,
    float* __restrict__ minval, int* __restrict__ done,
    float* __restrict__ out, int N) {
    const int t = (int)threadIdx.x;
    const int n = (int)blockIdx.x * 256 + t;
    float a0 = 0.f, a1 = 0.f;
    float v = 3.4e38f;
    if (n < N) {
        a0 = H3[n * 2 + 0]; a1 = H3[n * 2 + 1];
        int deg = cnt[n];
        const int* row = &eidx[(size_t)n * STRIDE];
        int j = 0;
        for (; j + 3 < deg; j += 4) {
            int i0 = row[j], i1 = row[j + 1], i2 = row[j + 2], i3 = row[j + 3];
            float2 q0 = *(const float2*)&hrel3[(size_t)i0 * 2];
            float2 q1 = *(const float2*)&hrel3[(size_t)i1 * 2];
            float2 q2 = *(const float2*)&hrel3[(size_t)i2 * 2];
            float2 q3 = *(const float2*)&hrel3[(size_t)i3 * 2];
            a0 += (q0.x + q1.x) + (q2.x + q3.x);
            a1 += (q0.y + q1.y) + (q2.y + q3.y);
        }
        for (; j < deg; ++j) {
            float2 q = *(const float2*)&hrel3[(size_t)row[j] * 2];
            a0 += q.x; a1 += q.y;
        }
        v = fminf(a0, a1);       // h.min() over FINAL h, before masking
    }
#pragma unroll
    for (int mm = 32; mm >= 1; mm >>= 1) v = fminf(v, __shfl_xor(v, mm, 64));
    __shared__ float s[4];
    __shared__ float gm;
    if ((t & 63) == 0) s[t >> 6] = v;
    __syncthreads();
    if (t == 0) {
        atomicMinF(minval, fminf(fminf(s[0], s[1]), fminf(s[2], s[3])));
        __threadfence();
        atomicAdd(done, 1);
        while (atomicAdd(done, 0) < (int)gridDim.x)  // 196 pollers: proven OK
            __builtin_amdgcn_s_sleep(2);
        gm = atomicAdd(minval, 0.0f);
    }
    __syncthreads();
    if (n < N) {
        float mn = gm - 1.0f;
        bool up = cs[n] >= ms[n] - 1;
        bool lo = cs[n] == 0;
        out[n * 2 + 0] = up ? mn : a0;
        out[n * 2 + 1] = lo ? mn : a1;
    }
}

// ---------------------------------------------------------------------------
extern "C" void kernel_launch(void* const* d_in, const int* in_sizes, int n_in,
                              void* d_out, int out_size, void* d_ws, size_t ws_size,
                              hipStream_t stream) {
    const float* x     = (const float*)d_in[0];
    const int* src     = (const int*)d_in[1];
    const int* dst     = (const int*)d_in[2];
    const int* etypes  = (const int*)d_in[3];
    const int* cellsz  = (const int*)d_in[4];
    const int* maxsz   = (const int*)d_in[5];
    const float* W1    = (const float*)d_in[6];
    const float* loop1 = (const float*)d_in[7];
    const float* b1    = (const float*)d_in[8];
    const float* W2    = (const float*)d_in[9];
    const float* loop2 = (const float*)d_in[10];
    const float* b2    = (const float*)d_in[11];
    const float* W3    = (const float*)d_in[12];
    const float* loop3 = (const float*)d_in[13];
    const float* b3    = (const float*)d_in[14];
    float* out = (float*)d_out;

    const int N = in_sizes[0] / 128;  // 50000
    const int E = in_sizes[1];        // 800000

    char* p = (char*)d_ws;
    auto alloc = [&](size_t bytes) -> void* {
        void* r = (void*)p;
        p += ((bytes + 255) / 256) * 256;
        return r;
    };
    ushortT* hrelb  = (ushortT*)alloc((size_t)2 * N * 64 * 2);  // 12.8 MB bf16
    ushortT* H1b    = (ushortT*)alloc((size_t)N * 64 * 2);      //  6.4 MB (self -> h1)
    ushortT* H2b    = (ushortT*)alloc((size_t)N * 64 * 2);      //  6.4 MB (h2)
    float* hrel3    = (float*)alloc((size_t)2 * N * 2 * 4);
    float* H3       = (float*)alloc((size_t)N * 2 * 4);
    int* cnt        = (int*)alloc((size_t)N * 4);
    int* eidx       = (int*)alloc((size_t)N * STRIDE * 4);      // 12.8 MB
    ushortT* BP1    = (ushortT*)alloc((size_t)3072 * 8 * 2);    // 48 KB
    ushortT* BP2p   = (ushortT*)alloc((size_t)1536 * 8 * 2);    // 24 KB (K=192)
    float* minval   = (float*)alloc(4);
    int* done       = (int*)alloc(4);

    const int NBINS = (N + 127) >> 7;                           // 391
    int* bincnt     = (int*)alloc((size_t)NBINS * 4);
    int2* binbuf    = (int2*)alloc((size_t)NBINS * BINCAP * 8); // 8.0 MB
    (void)ws_size; (void)n_in; (void)out_size;

    const int NB_N   = (N + 255) / 256;      // 196
    const int NTILES = (N + 63) / 64;        // 782
    const int NB_W   = (N + 3) / 4;          // 12500
    const int NBA    = (E + 4095) / 4096;    // 196 phase-A blocks
    const int NB_AG  = (N + 63) / 64;        // 782 (64 nodes each)

    // K0: weight pack + bincnt/minval/done init
    pack_init_kernel<<<18, 256, 0, stream>>>(
        W1, loop1, W2, loop2, BP1, BP2p, bincnt, minval, done, NBINS);

    // K1: phase-A binning || layer-1 MFMA GEMM
    k1_kernel<<<NBA + NTILES, 256, 0, stream>>>(
        x, BP1, b1, hrelb, H1b,
        src, dst, etypes, bincnt, binbuf, N, E, NBINS, NBA);

    // AG1: phase0 scatter + layer-1 aggregation -> h1 (in place in H1b)
    ag1_kernel<<<NB_AG, 512, 0, stream>>>(
        hrelb, bincnt, binbuf, eidx, cnt, H1b, N);

    // AG2p: layer-2 aggregate-then-transform (K=192 MFMA) -> h2
    ag2p_kernel<<<NB_AG, 512, 0, stream>>>(
        H1b, BP2p, b2, eidx, cnt, H2b, N);

    // K3p: layer-3 transform (coalesced)
    k3p_kernel<<<NB_W, 256, 0, stream>>>(H2b, W3, loop3, b3, hrel3, H3, N);

    // A3M: layer-3 aggregation + global min (spin barrier) + mask
    a3m_mask_kernel<<<NB_N, 256, 0, stream>>>(hrel3, eidx, cnt, H3,
                                              cellsz, maxsz, minval, done, out, N);
}